// Round 1
// 378.876 us; speedup vs baseline: 1.1046x; 1.1046x over previous
//
#include <hip/hip_runtime.h>
#include <hip/hip_bf16.h>
#include <math.h>

#define DIMV 512
#define NTOK 16384   // B*P*N = 2*8*1024
#define NSEQ 1024
#define HEADSV 8
#define PPV 8
#define DHEAD 64
#define QKVW 1536
#define HIDV 2048
#define SC2 0.18033688011112042f   // 0.125 * log2(e)

typedef unsigned short ushort;
typedef __attribute__((ext_vector_type(8))) short short8;
typedef __attribute__((ext_vector_type(8))) unsigned short ushort8;
typedef __attribute__((ext_vector_type(4))) unsigned short ushortx4;
typedef __attribute__((ext_vector_type(4))) float floatx4;

__device__ __forceinline__ float bf2f(ushort u){
  union { unsigned int i; float f; } c; c.i = ((unsigned int)u) << 16; return c.f;
}
// fast RNE f32->bf16 (finite values; no NaN branch): 3 VALU
__device__ __forceinline__ ushort f2bf(float f){
  union { float f; unsigned int i; } c; c.f = f;
  unsigned int u = c.i + 0x7fffu + ((c.i >> 16) & 1u);
  return (ushort)(u >> 16);
}
// truncating f32->bf16 (1 VALU) — for P only (bias cancels in softmax ratio)
__device__ __forceinline__ ushort f2bf_t(float f){
  union { float f; unsigned int i; } c; c.f = f;
  return (ushort)(c.i >> 16);
}
__device__ __forceinline__ void async_copy16(const void* gptr, void* lptr){
  __builtin_amdgcn_global_load_lds((const __attribute__((address_space(1))) void*)gptr,
                                   (__attribute__((address_space(3))) void*)lptr, 16, 0, 0);
}
// tanh-form GELU via one v_exp_f32: x * sigmoid(1.5957691x + 0.0713548x^3)
__device__ __forceinline__ float fast_gelu(float x){
  float u = x * (2.3022084f + 0.1029435f * x * x);   // (2u)*log2(e)
  return x * __builtin_amdgcn_rcpf(1.f + exp2f(-u));
}

__device__ __forceinline__ void wave_reduce2(float& a, float& b){
  #pragma unroll
  for (int off = 32; off > 0; off >>= 1){
    a += __shfl_down(a, off, 64);
    b += __shfl_down(b, off, 64);
  }
}

// ---- fused prep kernel: LN (blocks [0,16384)) + 4 weight transposes ----
__device__ __forceinline__ void wtrans_body(const float* __restrict__ W,
    __hip_bfloat16* __restrict__ Wt, int K, int N, int bx, int by, int t,
    float* tile /* 32*33 */){
  int bn = bx * 32, bk = by * 32;
  int tx = t & 31, ty = t >> 5;
  #pragma unroll
  for (int i = 0; i < 32; i += 8)
    tile[(ty + i) * 33 + tx] = W[(size_t)(bk + ty + i) * N + bn + tx];
  __syncthreads();
  #pragma unroll
  for (int i = 0; i < 32; i += 8)
    Wt[(size_t)(bn + ty + i) * K + bk + tx] = __float2bfloat16(tile[tx * 33 + ty + i]);
}

__global__ __launch_bounds__(256) void prep_kernel(const float* __restrict__ x,
    const float* __restrict__ w0, const float* __restrict__ b0,
    const float* __restrict__ w1ln, const float* __restrict__ b1ln,
    __hip_bfloat16* __restrict__ x1, __hip_bfloat16* __restrict__ h,
    const float* __restrict__ wqkv, __hip_bfloat16* __restrict__ wqkvT,
    const float* __restrict__ wo,   __hip_bfloat16* __restrict__ woT,
    const float* __restrict__ w1,   __hip_bfloat16* __restrict__ w1T,
    const float* __restrict__ w2,   __hip_bfloat16* __restrict__ w2T){
  __shared__ float smem[32 * 33];
  int bid = blockIdx.x;
  int t = threadIdx.x;
  if (bid >= NTOK){
    int r = bid - NTOK;
    if (r < 768)        wtrans_body(wqkv, wqkvT, 512, 1536, r % 48, r / 48, t, smem);
    else if (r < 1024){ r -= 768;  wtrans_body(wo, woT, 512, 512,  r % 16, r / 16, t, smem); }
    else if (r < 2048){ r -= 1024; wtrans_body(w1, w1T, 512, 2048, r % 64, r / 64, t, smem); }
    else             { r -= 2048; wtrans_body(w2, w2T, 2048, 512, r % 16, r / 16, t, smem); }
    return;
  }
  // ---- double LN ----
  float* sm = smem;
  size_t row = bid;
  const float2* xr = (const float2*)(x + row * DIMV);
  float2 v = xr[t];
  float s = v.x + v.y;
  float sq = v.x * v.x + v.y * v.y;
  wave_reduce2(s, sq);
  int wid = t >> 6, lane = t & 63;
  if (lane == 0){ sm[wid] = s; sm[8 + wid] = sq; }
  __syncthreads();
  s  = sm[0] + sm[1] + sm[2] + sm[3];
  sq = sm[8] + sm[9] + sm[10] + sm[11];
  float mu = s * (1.f / DIMV);
  float var = sq * (1.f / DIMV) - mu * mu;
  float r = rsqrtf(var + 1e-5f);
  float2 ww = ((const float2*)w0)[t];
  float2 bb = ((const float2*)b0)[t];
  float2 y;
  y.x = (v.x - mu) * r * ww.x + bb.x;
  y.y = (v.y - mu) * r * ww.y + bb.y;
  ushort2 xb; xb.x = f2bf(y.x); xb.y = f2bf(y.y);
  ((ushort2*)(x1 + row * DIMV))[t] = xb;
  float s2 = y.x + y.y, sq2 = y.x * y.x + y.y * y.y;
  wave_reduce2(s2, sq2);
  __syncthreads();
  if (lane == 0){ sm[wid] = s2; sm[8 + wid] = sq2; }
  __syncthreads();
  s2  = sm[0] + sm[1] + sm[2] + sm[3];
  sq2 = sm[8] + sm[9] + sm[10] + sm[11];
  float mu2 = s2 * (1.f / DIMV);
  float var2 = sq2 * (1.f / DIMV) - mu2 * mu2;
  float r2 = rsqrtf(var2 + 1e-5f);
  float2 w1v = ((const float2*)w1ln)[t];
  float2 b1v = ((const float2*)b1ln)[t];
  float hx = (y.x - mu2) * r2 * w1v.x + b1v.x;
  float hy = (y.y - mu2) * r2 * w1v.y + b1v.y;
  ushort2 hb; hb.x = f2bf(hx); hb.y = f2bf(hy);
  ((ushort2*)(h + row * DIMV))[t] = hb;
}

// MFMA bf16 GEMM: BK=32, 128x128 tile, XCD-swizzled 1D grid.
// Double-buffered LDS + raw s_barrier + counted vmcnt (never drained in-loop):
// prefetch of tile k+1 stays in flight across the barrier (T3/T4-lite).
// SWAP=0: D-layout col=l&15 -> N (needed for qkv's transposed-V store).
// SWAP=1: operands swapped -> acc reg holds 4 consecutive N-cols -> 8B/16B
//         vectorized epilogue stores (wo / w1 / w2 GEMMs).
template<int SWAP>
__global__ __launch_bounds__(256) void gemm_mfma(
    const __hip_bfloat16* __restrict__ A,
    const __hip_bfloat16* __restrict__ Bt,
    const float* __restrict__ bias,
    const __hip_bfloat16* __restrict__ Rb,
    float* __restrict__ Cf,
    __hip_bfloat16* __restrict__ Cb,
    ushort* __restrict__ vt,
    int M, int N, int K, int gx, int dogelu)
{
  __shared__ __hip_bfloat16 As[2][128 * 32];
  __shared__ __hip_bfloat16 Bs[2][128 * 32];
  int tid = threadIdx.x;
  int w = tid >> 6, l = tid & 63;

  int bid = blockIdx.x;
  int xcd = bid & 7, idx = bid >> 3;
  int xl = idx % gx, yl = idx / gx;
  size_t bm = (size_t)(xcd * 16 + yl) * 128;
  size_t bn = (size_t)xl * 128;
  int wm = (w & 1) * 64, wn = (w >> 1) * 64;

  int srow = w * 16 + (l >> 2);
  int scol = (l & 3) * 8;
  const __hip_bfloat16* Ag0 = A + (bm + srow) * K + scol;
  const __hip_bfloat16* Ag1 = A + (bm + 64 + srow) * K + scol;
  const __hip_bfloat16* Bg0 = Bt + (bn + srow) * K + scol;
  const __hip_bfloat16* Bg1 = Bt + (bn + 64 + srow) * K + scol;
  int lo = srow * 32 + scol;

  floatx4 acc[4][4] = {};
  int fm = l & 15;
  int quad = l >> 4;
  int fq = quad * 8;

  // prologue: stage tile 0 into buffer 0
  async_copy16(Ag0, &As[0][lo]);
  async_copy16(Ag1, &As[0][lo + 64 * 32]);
  async_copy16(Bg0, &Bs[0][lo]);
  async_copy16(Bg1, &Bs[0][lo + 64 * 32]);

  int nk = K >> 5;
  for (int it = 0; it < nk; ++it){
    int cur = it & 1;
    if (it + 1 < nk){
      int nxt = cur ^ 1;
      int k0 = (it + 1) << 5;
      async_copy16(Ag0 + k0, &As[nxt][lo]);
      async_copy16(Ag1 + k0, &As[nxt][lo + 64 * 32]);
      async_copy16(Bg0 + k0, &Bs[nxt][lo]);
      async_copy16(Bg1 + k0, &Bs[nxt][lo + 64 * 32]);
      // wait only for the CURRENT tile's 4 copies; next tile's stay in flight
      asm volatile("s_waitcnt vmcnt(4)\n\ts_barrier" ::: "memory");
    } else {
      asm volatile("s_waitcnt vmcnt(0)\n\ts_barrier" ::: "memory");
    }
    const __hip_bfloat16* Ab = As[cur];
    const __hip_bfloat16* Bb = Bs[cur];
    short8 af[4], bf[4];
    #pragma unroll
    for (int i = 0; i < 4; i++){
      af[i] = *(const short8*)&Ab[(wm + i * 16 + fm) * 32 + fq];
      bf[i] = *(const short8*)&Bb[(wn + i * 16 + fm) * 32 + fq];
    }
    #pragma unroll
    for (int mi = 0; mi < 4; mi++)
      #pragma unroll
      for (int ni = 0; ni < 4; ni++){
        if (SWAP)
          acc[mi][ni] = __builtin_amdgcn_mfma_f32_16x16x32_bf16(bf[ni], af[mi], acc[mi][ni], 0, 0, 0);
        else
          acc[mi][ni] = __builtin_amdgcn_mfma_f32_16x16x32_bf16(af[mi], bf[ni], acc[mi][ni], 0, 0, 0);
      }
    // drain LDS reads, but NOT vmcnt, before releasing the buffer
    asm volatile("s_waitcnt lgkmcnt(0)\n\ts_barrier" ::: "memory");
  }

  int rq = quad * 4;
  if (SWAP){
    // D layout (swapped): row = bm+wm+mi*16+(l&15), col = bn+wn+ni*16+quad*4+r
    #pragma unroll
    for (int mi = 0; mi < 4; mi++){
      size_t row = bm + wm + mi * 16 + fm;
      size_t rbase = row * (size_t)N + bn + wn + rq;
      #pragma unroll
      for (int ni = 0; ni < 4; ni++){
        size_t idx2 = rbase + ni * 16;
        floatx4 v = acc[mi][ni];
        if (bias){
          floatx4 bv = *(const floatx4*)(bias + bn + wn + ni * 16 + rq);
          #pragma unroll
          for (int r2 = 0; r2 < 4; r2++) v[r2] += bv[r2];
        }
        if (dogelu){
          #pragma unroll
          for (int r2 = 0; r2 < 4; r2++) v[r2] = fast_gelu(v[r2]);
        }
        if (Rb){
          ushortx4 rb = *(const ushortx4*)((const ushort*)Rb + idx2);
          #pragma unroll
          for (int r2 = 0; r2 < 4; r2++) v[r2] += bf2f(rb[r2]);
        }
        if (Cb){
          ushortx4 ob;
          #pragma unroll
          for (int r2 = 0; r2 < 4; r2++) ob[r2] = f2bf(v[r2]);
          *(ushortx4*)((ushort*)Cb + idx2) = ob;
        } else {
          *(floatx4*)(Cf + idx2) = v;
        }
      }
    }
  } else {
    // D layout (orig): col = l&15, row = quad*4 + reg
    if (vt && bn >= 1024){
      // ---- qkv V-columns: write transposed into vt[slice][d][n] ----
      int b = (int)(bm >> 13), p = (int)((bm >> 10) & 7);
      int n0 = (int)(bm & 1023) + wm + rq;
      int cbase = (int)bn + wn - 1024;
      #pragma unroll
      for (int ni = 0; ni < 4; ni++){
        int cc = cbase + ni * 16 + fm;
        int hh = cc >> 6, dd = cc & 63;
        ushort* vdst = vt + ((size_t)((b * 8 + hh) * 8 + p)) * 65536 + (size_t)dd * 1024;
        #pragma unroll
        for (int mi = 0; mi < 4; mi++){
          ushortx4 v4;
          v4[0] = f2bf(acc[mi][ni][0]); v4[1] = f2bf(acc[mi][ni][1]);
          v4[2] = f2bf(acc[mi][ni][2]); v4[3] = f2bf(acc[mi][ni][3]);
          *(ushortx4*)(vdst + n0 + mi * 16) = v4;
        }
      }
    } else if (Cb){
      float scl = (vt && bn < 512) ? SC2 : 1.f;
      #pragma unroll
      for (int ni = 0; ni < 4; ni++){
        size_t col = bn + wn + ni * 16 + fm;
        float bv = bias ? bias[col] : 0.f;
        #pragma unroll
        for (int mi = 0; mi < 4; mi++){
          #pragma unroll
          for (int r2 = 0; r2 < 4; r2++){
            size_t row = bm + wm + mi * 16 + rq + r2;
            float v = acc[mi][ni][r2];
            if (vt) v *= scl;
            v += bv;
            if (dogelu) v = fast_gelu(v);
            size_t idx2 = row * N + col;
            if (Rb) v += bf2f(((const ushort*)Rb)[idx2]);
            ((ushort*)Cb)[idx2] = f2bf(v);
          }
        }
      }
    } else {
      #pragma unroll
      for (int ni = 0; ni < 4; ni++){
        size_t col = bn + wn + ni * 16 + fm;
        float bv = bias ? bias[col] : 0.f;
        #pragma unroll
        for (int mi = 0; mi < 4; mi++){
          #pragma unroll
          for (int r2 = 0; r2 < 4; r2++){
            size_t row = bm + wm + mi * 16 + rq + r2;
            float v = acc[mi][ni][r2] + bv;
            if (dogelu) v = fast_gelu(v);
            size_t idx2 = row * N + col;
            if (Rb) v += bf2f(((const ushort*)Rb)[idx2]);
            Cf[idx2] = v;
          }
        }
      }
    }
  }
}

// MFMA flash attention. Q pre-scaled by SC2 (folded into qkv GEMM).
// Double-buffered K/V staging with counted vmcnt; PV operands swapped so the
// output epilogue vectorizes (8B stores), lacc via mfma(ones, pf).
__global__ __launch_bounds__(256) void attn_mfma(const __hip_bfloat16* __restrict__ qkvp,
                                                 const ushort* __restrict__ vt,
                                                 __hip_bfloat16* __restrict__ outp){
  __shared__ ushort Ks[2][64 * 64];
  __shared__ ushort Vs[2][64 * 64];
  __shared__ ushort Ps[4][32 * 72];
  int tid = threadIdx.x;
  int w = tid >> 6, l = tid & 63;
  int r15 = l & 15, quad = l >> 4, fq = quad * 8;
  int slice = blockIdx.x & 127;
  int qc = blockIdx.x >> 7;
  int b = slice >> 6, hh = (slice >> 3) & 7, p = slice & 7;
  const ushort* base = (const ushort*)qkvp + (size_t)(b * PPV + p) * NSEQ * QKVW;
  const ushort* kb = base + 512 + hh * DHEAD;
  const ushort* vb = vt + (size_t)slice * 65536;

  int s0 = w * 64 + l, s1 = 256 + w * 64 + l;
  int row0 = s0 >> 3, row1 = s1 >> 3;
  int gc0 = (s0 & 7) ^ (row0 & 7), gc1 = (s1 & 7) ^ (row1 & 7);
  const ushort* kp0 = kb + (size_t)row0 * QKVW + gc0 * 8;
  const ushort* kp1 = kb + (size_t)row1 * QKVW + gc1 * 8;
  const ushort* vp0 = vb + (size_t)row0 * 1024 + gc0 * 8;
  const ushort* vp1 = vb + (size_t)row1 * 1024 + gc1 * 8;

  // prologue: stage tile 0 into buffer 0
  async_copy16(kp0, &Ks[0][s0 * 8]);
  async_copy16(kp1, &Ks[0][s1 * 8]);
  async_copy16(vp0, &Vs[0][s0 * 8]);
  async_copy16(vp1, &Vs[0][s1 * 8]);

  int q0 = qc * 128 + w * 32;
  short8 qf[2][2];
  #pragma unroll
  for (int mi = 0; mi < 2; mi++)
    #pragma unroll
    for (int kk = 0; kk < 2; kk++)
      qf[mi][kk] = *(const short8*)(base + (size_t)(q0 + mi * 16 + r15) * QKVW + hh * DHEAD + kk * 32 + fq);

  floatx4 o[2][4] = {};
  floatx4 lacc[2] = {};
  short8 ones;
  #pragma unroll
  for (int j = 0; j < 8; j++) ones[j] = (short)0x3F80;

  int sw = r15 & 7;

  for (int it = 0; it < NSEQ / 64; ++it){
    int cur = it & 1;
    if (it + 1 < NSEQ / 64){
      int nxt = cur ^ 1;
      size_t m0 = (size_t)(it + 1) * 64;
      async_copy16(kp0 + m0 * QKVW, &Ks[nxt][s0 * 8]);
      async_copy16(kp1 + m0 * QKVW, &Ks[nxt][s1 * 8]);
      async_copy16(vp0 + m0, &Vs[nxt][s0 * 8]);
      async_copy16(vp1 + m0, &Vs[nxt][s1 * 8]);
      asm volatile("s_waitcnt vmcnt(4)\n\ts_barrier" ::: "memory");
    } else {
      asm volatile("s_waitcnt vmcnt(0)\n\ts_barrier" ::: "memory");
    }
    const ushort* Kb = Ks[cur];
    const ushort* Vb = Vs[cur];

    floatx4 s[2][4] = {};
    #pragma unroll
    for (int ni = 0; ni < 4; ni++){
      int row = ni * 16 + r15;
      short8 kf0 = *(const short8*)&Kb[row * 64 + (quad ^ sw) * 8];
      short8 kf1 = *(const short8*)&Kb[row * 64 + ((4 + quad) ^ sw) * 8];
      #pragma unroll
      for (int mi = 0; mi < 2; mi++){
        s[mi][ni] = __builtin_amdgcn_mfma_f32_16x16x32_bf16(qf[mi][0], kf0, s[mi][ni], 0, 0, 0);
        s[mi][ni] = __builtin_amdgcn_mfma_f32_16x16x32_bf16(qf[mi][1], kf1, s[mi][ni], 0, 0, 0);
      }
    }

    // P = exp2(S) (Q pre-scaled); truncating bf16 (bias cancels via l from P)
    #pragma unroll
    for (int mi = 0; mi < 2; mi++)
      #pragma unroll
      for (int ni = 0; ni < 4; ni++)
        #pragma unroll
        for (int r = 0; r < 4; r++)
          Ps[w][(mi * 16 + quad * 4 + r) * 72 + ni * 16 + r15] = f2bf_t(exp2f(s[mi][ni][r]));

    short8 pf[2][2];
    #pragma unroll
    for (int mi = 0; mi < 2; mi++)
      #pragma unroll
      for (int kk = 0; kk < 2; kk++)
        pf[mi][kk] = *(const short8*)&Ps[w][(mi * 16 + r15) * 72 + kk * 32 + fq];

    // row-sums: ones as A-operand -> col(l&15) indexes P-row n = mi*16+r15
    #pragma unroll
    for (int mi = 0; mi < 2; mi++)
      #pragma unroll
      for (int kk = 0; kk < 2; kk++)
        lacc[mi] = __builtin_amdgcn_mfma_f32_16x16x32_bf16(ones, pf[mi][kk], lacc[mi], 0, 0, 0);

    // PV swapped: o[mi][dj] has n = mi*16+r15 (fixed/lane), d = dj*16+quad*4+r
    #pragma unroll
    for (int dj = 0; dj < 4; dj++){
      int d = dj * 16 + r15;
      #pragma unroll
      for (int kk = 0; kk < 2; kk++){
        short8 vf = *(const short8*)&Vb[d * 64 + (((kk * 4 + quad)) ^ sw) * 8];
        #pragma unroll
        for (int mi = 0; mi < 2; mi++)
          o[mi][dj] = __builtin_amdgcn_mfma_f32_16x16x32_bf16(vf, pf[mi][kk], o[mi][dj], 0, 0, 0);
      }
    }
    asm volatile("s_waitcnt lgkmcnt(0)\n\ts_barrier" ::: "memory");
  }

  #pragma unroll
  for (int mi = 0; mi < 2; mi++){
    float inv = __builtin_amdgcn_rcpf(lacc[mi][0]);
    size_t n = q0 + mi * 16 + r15;
    ushort* orow = (ushort*)outp + ((size_t)((b * HEADSV + hh) * NSEQ + n)) * DIMV + p * DHEAD + quad * 4;
    #pragma unroll
    for (int dj = 0; dj < 4; dj++){
      ushortx4 ov;
      #pragma unroll
      for (int r = 0; r < 4; r++) ov[r] = f2bf(o[mi][dj][r] * inv);
      *(ushortx4*)(orow + dj * 16) = ov;
    }
  }
}

extern "C" void kernel_launch(void* const* d_in, const int* in_sizes, int n_in,
                              void* d_out, int out_size, void* d_ws, size_t ws_size,
                              hipStream_t stream){
  (void)in_sizes; (void)n_in; (void)out_size; (void)ws_size;
  const float* x    = (const float*)d_in[0];
  const float* lw0  = (const float*)d_in[1];
  const float* lb0  = (const float*)d_in[2];
  const float* lw1  = (const float*)d_in[3];
  const float* lb1  = (const float*)d_in[4];
  const float* wqkv = (const float*)d_in[5];
  const float* wo   = (const float*)d_in[6];
  const float* bo   = (const float*)d_in[7];
  const float* w1   = (const float*)d_in[8];
  const float* b1   = (const float*)d_in[9];
  const float* w2   = (const float*)d_in[10];
  const float* b2   = (const float*)d_in[11];
  float* out = (float*)d_out;
  char* ws = (char*)d_ws;
  const size_t MB = 1024 * 1024;

  __hip_bfloat16* x1b  = (__hip_bfloat16*)(ws);
  ushort* vtbuf        = (ushort*)(ws + 32 * MB);
  __hip_bfloat16* x2b  = (__hip_bfloat16*)(ws + 64 * MB);
  __hip_bfloat16* wqkvT= (__hip_bfloat16*)(ws + 80 * MB);
  __hip_bfloat16* woT  = (__hip_bfloat16*)(ws + 82 * MB);
  __hip_bfloat16* w1T  = (__hip_bfloat16*)(ws + 83 * MB);
  __hip_bfloat16* w2T  = (__hip_bfloat16*)(ws + 85 * MB);
  __hip_bfloat16* hB   = (__hip_bfloat16*)(ws + 88 * MB);
  __hip_bfloat16* attnB= hB;
  __hip_bfloat16* qkvB = (__hip_bfloat16*)(ws + 104 * MB);
  __hip_bfloat16* tB   = (__hip_bfloat16*)(ws + 88 * MB);

  // 1) fused prep: LN (16384 blocks) + 4 weight transposes (3072 blocks)
  prep_kernel<<<NTOK + 3072, 256, 0, stream>>>(
      x, lw0, lb0, lw1, lb1, x1b, hB,
      wqkv, wqkvT, wo, woT, w1, w1T, w2, w2T);

  // 2) qkv = h @ w_qkv -> bf16 (Q scaled by SC2, K) + transposed V into vtbuf
  gemm_mfma<0><<<(QKVW / 128) * 128, 256, 0, stream>>>(
      hB, wqkvT, nullptr, nullptr, nullptr, qkvB, vtbuf,
      NTOK, QKVW, DIMV, QKVW / 128, 0);

  // 3) attention
  attn_mfma<<<1024, 256, 0, stream>>>(qkvB, vtbuf, attnB);

  // 4) x2b = attn @ w_o + b_o + x1b -> bf16
  gemm_mfma<1><<<(DIMV / 128) * 128, 256, 0, stream>>>(
      attnB, woT, bo, x1b, nullptr, x2b, nullptr,
      NTOK, DIMV, DIMV, DIMV / 128, 0);

  // 5) t = gelu_fast(x2b @ w1 + b1) -> bf16
  gemm_mfma<1><<<(HIDV / 128) * 128, 256, 0, stream>>>(
      x2b, w1T, b1, nullptr, nullptr, tB, nullptr,
      NTOK, HIDV, DIMV, HIDV / 128, 1);

  // 6) out = t @ w2 + b2 + x2b -> fp32
  gemm_mfma<1><<<(DIMV / 128) * 128, 256, 0, stream>>>(
      tB, w2T, b2, x2b, out, nullptr, nullptr,
      NTOK, DIMV, HIDV, DIMV / 128, 0);
}